// Round 1
// baseline (1672.005 us; speedup 1.0000x reference)
//
#include <hip/hip_runtime.h>

#define BB 64
#define SS 2048
#define HH 128

// LDS-only barrier: drains DS ops (lgkmcnt) but NOT outstanding global
// loads/stores -- keeps per-step prefetch/stores off the critical path.
__device__ __forceinline__ void lds_barrier() {
  asm volatile("s_waitcnt lgkmcnt(0)\n\ts_barrier" ::: "memory");
}

// ---------------------------------------------------------------------------
// GEMM: out[row][j] = in[row][:] @ W[:][j] + bias[j], K=N=128. (unchanged)
// ---------------------------------------------------------------------------
__global__ __launch_bounds__(256) void gemm128v2(const float* __restrict__ in,
                                                 const float* __restrict__ W,
                                                 const float* __restrict__ bias,
                                                 float* __restrict__ out) {
  __shared__ __align__(16) float xls[128 * 128];   // 64 KB
  __shared__ __align__(16) float wls[128 * 140];   // 70 KB (padded rows)
  const int t = threadIdx.x;
  const long row0 = (long)blockIdx.x * 128;

  {
    const float4* g4 = (const float4*)(in + row0 * 128);
    float4* l4 = (float4*)xls;
#pragma unroll
    for (int it = 0; it < 16; ++it) l4[t + 256 * it] = g4[t + 256 * it];
  }
  {
#pragma unroll
    for (int it = 0; it < 16; ++it) {
      const int fidx = (t + 256 * it) * 4;
      const int k = fidx >> 7, j = fidx & 127;
      const float4 v = *(const float4*)(W + fidx);
      *(float4*)(wls + k * 140 + j + 4 * (j >> 5)) = v;
    }
  }
  __syncthreads();

  const int rg = t >> 4, cg = t & 15;
  const float* xrow = xls + (rg * 8) * 128;
  const float* wcol = wls + cg * 8 + 4 * (cg >> 2);

  float4 acc0[8], acc1[8];
#pragma unroll
  for (int r = 0; r < 8; ++r) {
    acc0[r] = make_float4(0.f, 0.f, 0.f, 0.f);
    acc1[r] = make_float4(0.f, 0.f, 0.f, 0.f);
  }

  for (int k = 0; k < 128; k += 4) {
    float4 xv[8];
#pragma unroll
    for (int r = 0; r < 8; ++r) xv[r] = *(const float4*)(xrow + r * 128 + k);
#pragma unroll
    for (int kk = 0; kk < 4; ++kk) {
      const float* wr = wcol + (k + kk) * 140;
      const float4 w0 = *(const float4*)(wr);
      const float4 w1 = *(const float4*)(wr + 4);
#pragma unroll
      for (int r = 0; r < 8; ++r) {
        const float xs = (kk == 0) ? xv[r].x : (kk == 1) ? xv[r].y
                       : (kk == 2) ? xv[r].z : xv[r].w;
        acc0[r].x = fmaf(xs, w0.x, acc0[r].x);
        acc0[r].y = fmaf(xs, w0.y, acc0[r].y);
        acc0[r].z = fmaf(xs, w0.z, acc0[r].z);
        acc0[r].w = fmaf(xs, w0.w, acc0[r].w);
        acc1[r].x = fmaf(xs, w1.x, acc1[r].x);
        acc1[r].y = fmaf(xs, w1.y, acc1[r].y);
        acc1[r].z = fmaf(xs, w1.z, acc1[r].z);
        acc1[r].w = fmaf(xs, w1.w, acc1[r].w);
      }
    }
  }

  const float4 b0 = *(const float4*)(bias + cg * 8);
  const float4 b1 = *(const float4*)(bias + cg * 8 + 4);
  float* op = out + (row0 + rg * 8) * 128 + cg * 8;
#pragma unroll
  for (int r = 0; r < 8; ++r) {
    float4 o0, o1;
    o0.x = acc0[r].x + b0.x; o0.y = acc0[r].y + b0.y;
    o0.z = acc0[r].z + b0.z; o0.w = acc0[r].w + b0.w;
    o1.x = acc1[r].x + b1.x; o1.y = acc1[r].y + b1.y;
    o1.z = acc1[r].z + b1.z; o1.w = acc1[r].w + b1.w;
    *(float4*)(op + r * 128) = o0;
    *(float4*)(op + r * 128 + 4) = o1;
  }
}

// ---------------------------------------------------------------------------
// Recurrence + fused output projection.
// Decomposition: jg = tid>>4 (16 col-groups of 8 cols), kg = tid&15 (16
// k-ranges of 8). O=8 cuts the per-step h fan-out to 2 ds_read_b128/thread
// (8 wave-instrs/step/CU vs 32 at O=2: the measured ~384cyc DS floor).
// Reduce over kg = 4-level reduce-scatter tree (xor 1/2 are DPP quad_perm,
// xor 4/8 swizzles): each lane ends with the FULL sum for col jg*8+(kg&7).
// y_t = h_t @ Wo is computed one step late from the SAME h-slice registers
// (zero extra LDS reads) -> third GEMM kernel deleted.
// h layout: 16 chunks of 8 floats at stride 12 (48 B): reads 16B-aligned,
// <=2-way bank aliasing (free, m136); same for the scattered owner writes.
// ---------------------------------------------------------------------------
#define FMA8(hs, w0, w1, n)                                      \
  n##0 = fmaf(hs, (w0).x, n##0); n##1 = fmaf(hs, (w0).y, n##1);  \
  n##2 = fmaf(hs, (w0).z, n##2); n##3 = fmaf(hs, (w0).w, n##3);  \
  n##4 = fmaf(hs, (w1).x, n##4); n##5 = fmaf(hs, (w1).y, n##5);  \
  n##6 = fmaf(hs, (w1).z, n##6); n##7 = fmaf(hs, (w1).w, n##7);

// Reduce-scatter over the 16-lane group (kg = lane&15). Input: p0..p7 =
// partials for cols jg*8+0..7. Output: full sum over all 16 kg for col
// jg*8+(kg&7), valid on every lane (kg and kg^8 hold duplicates).
// At each level the lane keeps the cols whose bit matches its kg bit and
// sends the partner's half; provider-side ternaries give each lane exactly
// what its partner keeps (static reg indices only -- rule #20).
__device__ __forceinline__ float rs16(const int kg, float p0, float p1,
                                      float p2, float p3, float p4, float p5,
                                      float p6, float p7) {
  const bool b0 = kg & 1, b1 = kg & 2, b2 = kg & 4;
  const float q0 = (b0 ? p1 : p0) + __shfl_xor(b0 ? p0 : p1, 1);
  const float q1 = (b0 ? p3 : p2) + __shfl_xor(b0 ? p2 : p3, 1);
  const float q2 = (b0 ? p5 : p4) + __shfl_xor(b0 ? p4 : p5, 1);
  const float q3 = (b0 ? p7 : p6) + __shfl_xor(b0 ? p6 : p7, 1);
  const float r0 = (b1 ? q1 : q0) + __shfl_xor(b1 ? q0 : q1, 2);
  const float r1 = (b1 ? q3 : q2) + __shfl_xor(b1 ? q2 : q3, 2);
  float s = (b2 ? r1 : r0) + __shfl_xor(b2 ? r0 : r1, 4);
  s += __shfl_xor(s, 8);
  return s;
}

__global__ __launch_bounds__(256, 1) void rnn_fused(
    const float* __restrict__ xi, const float* __restrict__ Wh,
    const float* __restrict__ Wo, const float* __restrict__ bo,
    float* __restrict__ y) {
  __shared__ __align__(16) float hbuf[2][192];  // 16 chunks x (8+4 pad)
  const int tid = threadIdx.x;
  const int jg = tid >> 4;  // col-group: cols jg*8 .. jg*8+7
  const int kg = tid & 15;  // k-range:  k    kg*8 .. kg*8+7

  // weights in registers: wh/wo[2q+{0,1}] = W[kg*8+q][jg*8 + {0..3,4..7}]
  float4 wh[16], wo[16];
  {
    const float* wp = Wh + (kg * 8) * HH + jg * 8;
    const float* op = Wo + (kg * 8) * HH + jg * 8;
#pragma unroll
    for (int q = 0; q < 8; ++q) {
      wh[2 * q]     = *(const float4*)(wp + q * HH);
      wh[2 * q + 1] = *(const float4*)(wp + q * HH + 4);
      wo[2 * q]     = *(const float4*)(op + q * HH);
      wo[2 * q + 1] = *(const float4*)(op + q * HH + 4);
    }
  }
  const float bo_own = bo[jg * 8 + (kg & 7)];
  if (tid < 192) hbuf[0][tid] = 0.0f;  // h_{-1} = 0 (incl. pads)

  const float* xb = xi + (size_t)blockIdx.x * SS * HH;
  float* yb = y + (size_t)blockIdx.x * SS * HH;

  // xi prefetch: lanes kg<2 hold xi_t[jg*8 + (kg&1)*4 ..+4], pre-added to
  // exactly one partial per col before the reduce tree.
  constexpr int PF = 4;
  const int xoff = jg * 8 + (kg & 1) * 4;
  float4 pre[PF];
  if (kg < 2) {
#pragma unroll
    for (int p = 0; p < PF; ++p) pre[p] = *(const float4*)(xb + p * HH + xoff);
  }
  __syncthreads();

  const int rdoff = kg * 12;             // this thread's k-slice chunk
  const int wroff = jg * 12 + (kg & 7);  // write slot for col jg*8+(kg&7)

  for (int t0 = 0; t0 < SS; t0 += PF) {
#pragma unroll
    for (int p = 0; p < PF; ++p) {
      const int t = t0 + p;
      const float* hb = hbuf[p & 1];  // t&1 == p&1 (PF even, t0 multiple)
      const float4 h0 = *(const float4*)(hb + rdoff);
      const float4 h1 = *(const float4*)(hb + rdoff + 4);

      float a0 = 0.f, a1 = 0.f, a2 = 0.f, a3 = 0.f;
      float a4 = 0.f, a5 = 0.f, a6 = 0.f, a7 = 0.f;
      float z0 = 0.f, z1 = 0.f, z2 = 0.f, z3 = 0.f;
      float z4 = 0.f, z5 = 0.f, z6 = 0.f, z7 = 0.f;
      // recurrence matvec partials (a*) + output-proj partials (z*), both
      // from the same h-slice registers.
      FMA8(h0.x, wh[0], wh[1], a)
      FMA8(h0.y, wh[2], wh[3], a)
      FMA8(h0.z, wh[4], wh[5], a)
      FMA8(h0.w, wh[6], wh[7], a)
      FMA8(h1.x, wh[8], wh[9], a)
      FMA8(h1.y, wh[10], wh[11], a)
      FMA8(h1.z, wh[12], wh[13], a)
      FMA8(h1.w, wh[14], wh[15], a)
      FMA8(h0.x, wo[0], wo[1], z)
      FMA8(h0.y, wo[2], wo[3], z)
      FMA8(h0.z, wo[4], wo[5], z)
      FMA8(h0.w, wo[6], wo[7], z)
      FMA8(h1.x, wo[8], wo[9], z)
      FMA8(h1.y, wo[10], wo[11], z)
      FMA8(h1.z, wo[12], wo[13], z)
      FMA8(h1.w, wo[14], wo[15], z)

      if (kg < 2) {
        const float4 xv = pre[p];
        if (kg == 0) { a0 += xv.x; a1 += xv.y; a2 += xv.z; a3 += xv.w; }
        else         { a4 += xv.x; a5 += xv.y; a6 += xv.z; a7 += xv.w; }
        const int tn = t + PF;
        if (tn < SS) pre[p] = *(const float4*)(xb + (size_t)tn * HH + xoff);
      }

      const float s = rs16(kg, a0, a1, a2, a3, a4, a5, a6, a7);
      // tanh(v) = 1 - 2/(exp2(2v*log2e)+1); safe at +-inf
      const float ex = __builtin_amdgcn_exp2f(s * 2.8853900817779268f);
      const float hn =
          fmaxf(1.0f - 2.0f * __builtin_amdgcn_rcpf(ex + 1.0f), 0.0f);
      if (kg < 8) hbuf[(p & 1) ^ 1][wroff] = hn;  // h for step t+1

      // y_{t-1} = h_{t-1} @ Wo + bo (h_{t-1} is what we just consumed)
      const float sy = rs16(kg, z0, z1, z2, z3, z4, z5, z6, z7);
      if (t > 0 && kg < 8)
        yb[(size_t)(t - 1) * HH + jg * 8 + kg] = sy + bo_own;

      lds_barrier();
    }
  }

  // epilogue: y_{SS-1}. SS even -> h_{SS-1} sits in hbuf[0]; the loop's
  // final lds_barrier already made it visible.
  {
    const float4 h0 = *(const float4*)(hbuf[0] + rdoff);
    const float4 h1 = *(const float4*)(hbuf[0] + rdoff + 4);
    float z0 = 0.f, z1 = 0.f, z2 = 0.f, z3 = 0.f;
    float z4 = 0.f, z5 = 0.f, z6 = 0.f, z7 = 0.f;
    FMA8(h0.x, wo[0], wo[1], z)
    FMA8(h0.y, wo[2], wo[3], z)
    FMA8(h0.z, wo[4], wo[5], z)
    FMA8(h0.w, wo[6], wo[7], z)
    FMA8(h1.x, wo[8], wo[9], z)
    FMA8(h1.y, wo[10], wo[11], z)
    FMA8(h1.z, wo[12], wo[13], z)
    FMA8(h1.w, wo[14], wo[15], z)
    const float sy = rs16(kg, z0, z1, z2, z3, z4, z5, z6, z7);
    if (kg < 8) yb[(size_t)(SS - 1) * HH + jg * 8 + kg] = sy + bo_own;
  }
}

extern "C" void kernel_launch(void* const* d_in, const int* in_sizes, int n_in,
                              void* d_out, int out_size, void* d_ws, size_t ws_size,
                              hipStream_t stream) {
  const float* x  = (const float*)d_in[0];
  const float* Wi = (const float*)d_in[1];
  const float* Wh = (const float*)d_in[2];
  const float* b  = (const float*)d_in[3];
  const float* Wo = (const float*)d_in[4];
  const float* bo = (const float*)d_in[5];
  float* y  = (float*)d_out;
  float* xi = (float*)d_ws;  // 64 MB: xi = x @ Wi + b

  gemm128v2<<<(BB * SS) / 128, 256, 0, stream>>>(x, Wi, b, xi);
  rnn_fused<<<BB, 256, 0, stream>>>(xi, Wh, Wo, bo, y);
}